// Round 2
// baseline (1215.453 us; speedup 1.0000x reference)
//
#include <hip/hip_runtime.h>
#include <float.h>

// VectorQuantize: h=8 heads, c=2048 codes, d=64, b=8, t=2048 (n=16384 vec/head)
#define H   8
#define C   2048
#define D   64
#define NPH 16384     // vectors per head (b*t)
#define HD  512       // h*d
#define DECAYF 0.9f

// ---------------------------------------------------------------------------
// Kernel 0: e_sq[h,c] = sum_d ke[h,c,d]^2   (16384 entries)
// ---------------------------------------------------------------------------
__global__ __launch_bounds__(256) void vq_esq_kernel(const float* __restrict__ ke,
                                                     float* __restrict__ esq) {
    int i = blockIdx.x * 256 + threadIdx.x;   // 0 .. H*C-1
    const float* e = ke + (size_t)i * D;
    float s = 0.f;
#pragma unroll
    for (int d = 0; d < D; ++d) s = fmaf(e[d], e[d], s);
    esq[i] = s;
}

// ---------------------------------------------------------------------------
// Kernel 1: main VQ. 1024 blocks x 256 threads.
//   block: head = blk&7, chunk = blk>>3 -> 128 vectors
//   4 waves: wave&1 = codebook half, wave>>1 = vector group
//   Each thread: one x vector in 64 VGPRs, scans 1024 codes via wave-uniform
//   scalar loads of the codebook (v_fma v,v,s), tracks argmin.
//   __launch_bounds__(256,4): min 4 waves/EU -> 128-VGPR budget so xr[64]
//   stays in registers (round-1's bare launch_bounds gave VGPR=52 => spill,
//   299 MB scratch writes, 41% VALUBusy).
// ---------------------------------------------------------------------------
__global__ __launch_bounds__(256, 4) void vq_main_kernel(const float* __restrict__ x,
                                                         const float* __restrict__ ke,
                                                         const float* __restrict__ esq,
                                                         float* __restrict__ outq,
                                                         float* __restrict__ outi,
                                                         float* __restrict__ embsum) {
    __shared__ float s_best[128][2];
    __shared__ int   s_bi[128][2];

    const int tid  = threadIdx.x;
    const int lane = tid & 63;
    // force wave-uniformity so codebook reads become s_load
    const int wave_u = __builtin_amdgcn_readfirstlane(tid >> 6);
    const int half = wave_u & 1;        // which half of the codebook
    const int vgrp = wave_u >> 1;       // which 64-vector group

    const int h     = blockIdx.x & 7;
    const int chunk = blockIdx.x >> 3;          // 0..127
    const int vloc  = vgrp * 64 + lane;         // 0..127 within block
    const int n     = chunk * 128 + vloc;       // vector index within head

    // load x vector into registers: x[n*512 + h*64 + d]
    const float* xp = x + (size_t)n * HD + (size_t)h * D;
    float xr[D];
#pragma unroll
    for (int k = 0; k < D / 4; ++k) {
        float4 v = ((const float4*)xp)[k];
        xr[4 * k + 0] = v.x; xr[4 * k + 1] = v.y;
        xr[4 * k + 2] = v.z; xr[4 * k + 3] = v.w;
    }
    float xsq = 0.f;
#pragma unroll
    for (int d = 0; d < D; ++d) xsq = fmaf(xr[d], xr[d], xsq);

    const float* eh  = ke  + ((size_t)h * C + (size_t)half * (C / 2)) * D;
    const float* eqh = esq + (size_t)h * C + (size_t)half * (C / 2);

    float best = FLT_MAX;
    int   bi   = 0;

    for (int c = 0; c < C / 2; c += 8) {
        float acc[8];
#pragma unroll
        for (int j = 0; j < 8; ++j) acc[j] = 0.f;
#pragma unroll
        for (int dk = 0; dk < D; ++dk) {
            const float xv = xr[dk];
#pragma unroll
            for (int j = 0; j < 8; ++j)
                acc[j] = fmaf(xv, eh[(size_t)(c + j) * D + dk], acc[j]);
        }
#pragma unroll
        for (int j = 0; j < 8; ++j) {
            // match reference rounding: (x_sq - 2*dots) + e_sq
            float d2 = (xsq - 2.f * acc[j]) + eqh[c + j];
            if (d2 < best) { best = d2; bi = c + j; }   // first-min wins
        }
    }
    int bi_g = bi + half * (C / 2);

    s_best[vloc][half] = best;
    s_bi[vloc][half]   = bi_g;
    __syncthreads();

    if (half == 0) {
        float b1 = s_best[vloc][1];
        int   i1 = s_bi[vloc][1];
        if (b1 < best) { best = b1; bi_g = i1; }  // ties -> lower index (half 0)

        // index output: [b,t,h] => n*H + h  (written as float)
        outi[(size_t)n * H + h] = (float)bi_g;

        // quantized gather: out0[n*512 + h*64 + d] = ke[h, bi_g, d]
        const float* ev = ke + ((size_t)h * C + bi_g) * D;
        float* qo = outq + (size_t)n * HD + (size_t)h * D;
#pragma unroll
        for (int k = 0; k < D / 4; ++k)
            ((float4*)qo)[k] = ((const float4*)ev)[k];

        // scatter-add x into emb_sum[h, bi_g, :]
        float* es = embsum + ((size_t)h * C + bi_g) * D;
#pragma unroll
        for (int d = 0; d < D; ++d) atomicAdd(es + d, xr[d]);
    }
}

// ---------------------------------------------------------------------------
// Kernel 2: new_ke = key_optim ? ke + 0.9*(emb_sum - ke) : ke
// ---------------------------------------------------------------------------
__global__ __launch_bounds__(256) void vq_lerp_kernel(const float* __restrict__ ke,
                                                      const float* __restrict__ embsum,
                                                      const int* __restrict__ ko,
                                                      float* __restrict__ outk) {
    int i = (blockIdx.x * 256 + threadIdx.x) * 4;   // H*C*D = 1048576 floats
    const int on = ko[0];
    float4 k4 = *(const float4*)(ke + i);
    float4 s4 = *(const float4*)(embsum + i);
    float4 o4;
    if (on) {
        o4.x = k4.x + DECAYF * (s4.x - k4.x);
        o4.y = k4.y + DECAYF * (s4.y - k4.y);
        o4.z = k4.z + DECAYF * (s4.z - k4.z);
        o4.w = k4.w + DECAYF * (s4.w - k4.w);
    } else {
        o4 = k4;
    }
    *(float4*)(outk + i) = o4;
}

extern "C" void kernel_launch(void* const* d_in, const int* in_sizes, int n_in,
                              void* d_out, int out_size, void* d_ws, size_t ws_size,
                              hipStream_t stream) {
    const float* x  = (const float*)d_in[0];
    const float* ke = (const float*)d_in[1];
    const int*   ko = (const int*)d_in[2];

    float* out  = (float*)d_out;
    float* outq = out;                                   // 8,388,608 floats
    float* outi = out + (size_t)H * NPH * D;             // +131,072 floats
    float* outk = outi + (size_t)NPH * H;                // +1,048,576 floats

    float* embsum = (float*)d_ws;                        // H*C*D = 1,048,576 f32
    float* esq    = embsum + (size_t)H * C * D;          // 16,384 f32

    // zero the scatter accumulator every call (graph-replay safe)
    hipMemsetAsync(embsum, 0, (size_t)H * C * D * sizeof(float), stream);

    vq_esq_kernel<<<(H * C) / 256, 256, 0, stream>>>(ke, esq);
    vq_main_kernel<<<1024, 256, 0, stream>>>(x, ke, esq, outq, outi, embsum);
    vq_lerp_kernel<<<(H * C * D) / (256 * 4), 256, 0, stream>>>(ke, embsum, ko, outk);
}

// Round 3
// 855.651 us; speedup vs baseline: 1.4205x; 1.4205x over previous
//
#include <hip/hip_runtime.h>
#include <float.h>

// VectorQuantize: h=8 heads, c=2048 codes, d=64, b=8, t=2048 (n=16384 vec/head)
#define H   8
#define C   2048
#define D   64
#define NPH 16384     // vectors per head (b*t)
#define HD  512       // h*d
#define DECAYF 0.9f

// ---------------------------------------------------------------------------
// Kernel 0: e_sq[h,c] = sum_d ke[h,c,d]^2
// ---------------------------------------------------------------------------
__global__ __launch_bounds__(256) void vq_esq_kernel(const float* __restrict__ ke,
                                                     float* __restrict__ esq) {
    int i = blockIdx.x * 256 + threadIdx.x;   // 0 .. H*C-1
    const float* e = ke + (size_t)i * D;
    float s = 0.f;
#pragma unroll
    for (int d = 0; d < D; ++d) s = fmaf(e[d], e[d], s);
    esq[i] = s;
}

// ---------------------------------------------------------------------------
// Kernel 1: register-tiled distance GEMM + argmin.
//   1024 blocks x 256 threads. Block: head = blk&7 (aligns head<->XCD for L2
//   codebook locality), vtile = blk>>3 -> 128 vectors. 16 code-tiles of 128.
//   Thread (tx,ty) = (tid&15, tid>>4) owns an 8x8 acc tile: vecs ty*8..+7,
//   codes tx*8..+7 of each tile. Operands staged transposed in LDS, read as
//   ds_read_b128. All distance math bit-identical to the round-1 kernel
//   (fmaf over k ascending, (xsq-2dot)+esq, first-min tie-break).
// ---------------------------------------------------------------------------
// smem float offsets:
//   sx   [    0,  8192)  x^T tile [k][v] 64x128  (alive until scatter)
//   se   [ 8192, 16384)  e^T tile [k][c] 64x128  (aliased by rb/ri at end)
//   sxsq [16384, 16512)
//   sesq [16512, 16640)
//   sidx [16640, 16768)  (int)
//   rb = smem+8192 [16][128], ri = (int*)(smem+10240) [16][128]
#define SMEM_FLOATS 16768

__global__ __launch_bounds__(256, 2) void vq_main_kernel(const float* __restrict__ x,
                                                         const float* __restrict__ ke,
                                                         const float* __restrict__ esq,
                                                         float* __restrict__ outq,
                                                         float* __restrict__ outi,
                                                         float* __restrict__ embsum) {
    __shared__ __align__(16) float smem[SMEM_FLOATS];
    float* sx   = smem;
    float* se   = smem + 8192;
    float* sxsq = smem + 16384;
    float* sesq = smem + 16512;
    int*   sidx = (int*)(smem + 16640);

    const int tid = threadIdx.x;
    const int tx  = tid & 15;    // code group
    const int ty  = tid >> 4;    // vec group
    const int h   = blockIdx.x & 7;
    const int vt  = blockIdx.x >> 3;
    const int n0  = vt * 128;    // first vector of this block (within head)

    // ---- stage x^T: sx[k][v] = x[n0+v][h*64+k] ----
    {
        const int v  = tid >> 1;
        const int kb = (tid & 1) * 32;
        const float* xp = x + (size_t)(n0 + v) * HD + (size_t)h * D + kb;
#pragma unroll
        for (int i = 0; i < 8; ++i) {
            float4 w = ((const float4*)xp)[i];
            sx[(kb + 4 * i + 0) * 128 + v] = w.x;
            sx[(kb + 4 * i + 1) * 128 + v] = w.y;
            sx[(kb + 4 * i + 2) * 128 + v] = w.z;
            sx[(kb + 4 * i + 3) * 128 + v] = w.w;
        }
    }
    __syncthreads();

    // ---- xsq per vector (sequential fmaf over k: matches reference order) ----
    if (tid < 128) {
        float s = 0.f;
        for (int k = 0; k < 64; ++k) {
            float v = sx[k * 128 + tid];
            s = fmaf(v, v, s);
        }
        sxsq[tid] = s;
    }
    __syncthreads();

    // cache own vecs' xsq in registers
    float xq[8];
#pragma unroll
    for (int r = 0; r < 8; ++r) xq[r] = sxsq[ty * 8 + r];

    float best[8];
    int   bidx[8];
#pragma unroll
    for (int r = 0; r < 8; ++r) { best[r] = FLT_MAX; bidx[r] = 0x7fffffff; }

    // ---- loop over 16 code tiles ----
    for (int t = 0; t < 16; ++t) {
        const int cb = t * 128;
        __syncthreads();   // previous tile's readers done before overwriting se

        // stage e^T: se[k][c] = ke[h][cb+c][k]
        {
            const int c  = tid >> 1;
            const int kb = (tid & 1) * 32;
            const float* ep = ke + ((size_t)h * C + cb + c) * D + kb;
#pragma unroll
            for (int i = 0; i < 8; ++i) {
                float4 w = ((const float4*)ep)[i];
                se[(kb + 4 * i + 0) * 128 + c] = w.x;
                se[(kb + 4 * i + 1) * 128 + c] = w.y;
                se[(kb + 4 * i + 2) * 128 + c] = w.z;
                se[(kb + 4 * i + 3) * 128 + c] = w.w;
            }
        }
        if (tid < 128) sesq[tid] = esq[(size_t)h * C + cb + tid];
        __syncthreads();

        // 8x8 register-tile dot products over k
        float acc[8][8];
#pragma unroll
        for (int r = 0; r < 8; ++r)
#pragma unroll
            for (int j = 0; j < 8; ++j) acc[r][j] = 0.f;

#pragma unroll 4
        for (int k = 0; k < 64; ++k) {
            float4 xa0 = *(const float4*)&sx[k * 128 + ty * 8];
            float4 xa1 = *(const float4*)&sx[k * 128 + ty * 8 + 4];
            float4 eb0 = *(const float4*)&se[k * 128 + tx * 8];
            float4 eb1 = *(const float4*)&se[k * 128 + tx * 8 + 4];
            float xa[8] = {xa0.x, xa0.y, xa0.z, xa0.w, xa1.x, xa1.y, xa1.z, xa1.w};
            float eb[8] = {eb0.x, eb0.y, eb0.z, eb0.w, eb1.x, eb1.y, eb1.z, eb1.w};
#pragma unroll
            for (int r = 0; r < 8; ++r)
#pragma unroll
                for (int j = 0; j < 8; ++j)
                    acc[r][j] = fmaf(xa[r], eb[j], acc[r][j]);
        }

        // epilogue: d2 = (xsq - 2*dot) + esq ; running first-min
#pragma unroll
        for (int r = 0; r < 8; ++r) {
#pragma unroll
            for (int j = 0; j < 8; ++j) {
                float d2 = (xq[r] - 2.f * acc[r][j]) + sesq[tx * 8 + j];
                if (d2 < best[r]) { best[r] = d2; bidx[r] = cb + tx * 8 + j; }
            }
        }
    }

    // ---- cross-thread argmin reduction (rb/ri alias se) ----
    __syncthreads();
    float* rb = smem + 8192;
    int*   ri = (int*)(smem + 10240);
#pragma unroll
    for (int r = 0; r < 8; ++r) {
        rb[tx * 128 + ty * 8 + r] = best[r];
        ri[tx * 128 + ty * 8 + r] = bidx[r];
    }
    __syncthreads();
    if (tid < 128) {
        const int v = tid;
        float bb = FLT_MAX;
        int   bi = 0x7fffffff;
        for (int g = 0; g < 16; ++g) {
            float b = rb[g * 128 + v];
            int   i = ri[g * 128 + v];
            if (b < bb || (b == bb && i < bi)) { bb = b; bi = i; }
        }
        sidx[v] = bi;
        outi[(size_t)(n0 + v) * H + h] = (float)bi;   // [b,t,h]
    }
    __syncthreads();

    // ---- gather quantized vectors + scatter-add into emb_sum ----
    {
        const int v  = tid >> 1;
        const int db = (tid & 1) * 32;
        const int ci = sidx[v];
        const float* ev = ke + ((size_t)h * C + ci) * D + db;
        float* qo = outq + (size_t)(n0 + v) * HD + (size_t)h * D + db;
#pragma unroll
        for (int i = 0; i < 8; ++i)
            ((float4*)qo)[i] = ((const float4*)ev)[i];

        float* es = embsum + ((size_t)h * C + ci) * D + db;
#pragma unroll
        for (int d = 0; d < 32; ++d)
            atomicAdd(es + d, sx[(db + d) * 128 + v]);
    }
}

// ---------------------------------------------------------------------------
// Kernel 2: new_ke = key_optim ? ke + 0.9*(emb_sum - ke) : ke
// ---------------------------------------------------------------------------
__global__ __launch_bounds__(256) void vq_lerp_kernel(const float* __restrict__ ke,
                                                      const float* __restrict__ embsum,
                                                      const int* __restrict__ ko,
                                                      float* __restrict__ outk) {
    int i = (blockIdx.x * 256 + threadIdx.x) * 4;   // H*C*D = 1048576 floats
    const int on = ko[0];
    float4 k4 = *(const float4*)(ke + i);
    float4 s4 = *(const float4*)(embsum + i);
    float4 o4;
    if (on) {
        o4.x = k4.x + DECAYF * (s4.x - k4.x);
        o4.y = k4.y + DECAYF * (s4.y - k4.y);
        o4.z = k4.z + DECAYF * (s4.z - k4.z);
        o4.w = k4.w + DECAYF * (s4.w - k4.w);
    } else {
        o4 = k4;
    }
    *(float4*)(outk + i) = o4;
}

extern "C" void kernel_launch(void* const* d_in, const int* in_sizes, int n_in,
                              void* d_out, int out_size, void* d_ws, size_t ws_size,
                              hipStream_t stream) {
    const float* x  = (const float*)d_in[0];
    const float* ke = (const float*)d_in[1];
    const int*   ko = (const int*)d_in[2];

    float* out  = (float*)d_out;
    float* outq = out;                                   // 8,388,608 floats
    float* outi = out + (size_t)H * NPH * D;             // +131,072 floats
    float* outk = outi + (size_t)NPH * H;                // +1,048,576 floats

    float* embsum = (float*)d_ws;                        // H*C*D f32
    float* esq    = embsum + (size_t)H * C * D;          // 16,384 f32

    // zero the scatter accumulator every call (graph-replay safe)
    hipMemsetAsync(embsum, 0, (size_t)H * C * D * sizeof(float), stream);

    vq_esq_kernel<<<(H * C) / 256, 256, 0, stream>>>(ke, esq);
    vq_main_kernel<<<1024, 256, 0, stream>>>(x, ke, esq, outq, outi, embsum);
    vq_lerp_kernel<<<(H * C * D) / (256 * 4), 256, 0, stream>>>(ke, embsum, ko, outk);
}